// Round 5
// baseline (110.701 us; speedup 1.0000x reference)
//
#include <hip/hip_runtime.h>
#include <math.h>

// ---------------------------------------------------------------------------
// ScatteringNetwork:
//   img [8,1,256,256] f32, psi_re/psi_im [10,1,11,11] f32, blur_k [7,7] f32
//   out: concat([s0(1ch), s1_out(10ch), s2_out(100ch)]) at 32x32 -> [8, 111*1024]
//
// blur(conv(x,psi))[::8] == conv(x, psi (*) blur)[::8]  (17x17 combined kernel
// at 32x32 positions), 4 clip-variants for the Y==0/X==0 blur-pad edge.
//
// Morlet bank is rank-1 separable: psi[i][j] = psi[i][5]*psi[5][j]/psi[5][5].
// k_s1 uses H_j=psi[5][j], F_i=psi[i][5], rescales |.| by 1/|psi[5][5]|.
//
// R5 fix: composed-conv weights were wave-uniform s_loads -> scalar-cache
// throughput wall (VALUBusy 11%). hu=(tid>>7)&1 is not provably uniform ->
// compiler emits VMEM global_load (deep vmcnt queue, L1-hot combT). Border
// fix = half-wave global-read units (no LDS, no bank conflicts).
//
// ws layout (floats): [0) s1abs 8*10*65536 ; [5242880) combT 4*289*10
// ---------------------------------------------------------------------------

#define S1ABS_OFF 0
#define COMBT_OFF 5242880

// ---------------- k_s1: separable Morlet |conv|, wave-per-channel ----------
__global__ __launch_bounds__(640) void k_s1(const float* __restrict__ img,
                                            const float* __restrict__ psi_re,
                                            const float* __restrict__ psi_im,
                                            const float* __restrict__ blur,
                                            float* __restrict__ s1abs,
                                            float* __restrict__ combT) {
    if (blockIdx.z == 8) {        // combT setup slice
        int g = (blockIdx.y * 16 + blockIdx.x) * 640 + threadIdx.x;
        if (g < 11560) {
            int k = g % 10; int t = g / 10; int ij = t % 289; int v = t / 289;
            int i = ij / 17, j = ij % 17;
            int pmin = (v & 2) ? 3 : 0, qmin = (v & 1) ? 3 : 0;
            float s = 0.f;
            for (int p = pmin; p < 7; ++p) {
                int ii = i - p; if (ii < 0 || ii >= 11) continue;
                for (int q = qmin; q < 7; ++q) {
                    int jj = j - q; if (jj < 0 || jj >= 11) continue;
                    s += blur[p * 7 + q] * psi_re[k * 121 + ii * 11 + jj];
                }
            }
            combT[v * 2890 + ij * 10 + k] = s;
        }
        return;
    }

    __shared__ float timg[26 * 27];
    __shared__ float inter[10][26 * 34];
    int tid = threadIdx.x;
    int lane = tid & 63;
    int c = __builtin_amdgcn_readfirstlane(tid >> 6);   // wave = channel 0..9

    const float* pr = psi_re + c * 121;
    const float* pi = psi_im + c * 121;
    float hr[11], hi[11], fr[11], fi[11];
#pragma unroll
    for (int j = 0; j < 11; ++j) { hr[j] = pr[55 + j]; hi[j] = pi[55 + j]; }
#pragma unroll
    for (int i = 0; i < 11; ++i) { fr[i] = pr[i * 11 + 5]; fi[i] = pi[i * 11 + 5]; }
    float dr = pr[60], di = pi[60];
    float inv = rsqrtf(dr * dr + di * di);

    int n = blockIdx.z;
    int y0 = blockIdx.y * 16, x0 = blockIdx.x * 16;
    const float* im = img + n * 65536;
    for (int idx = tid; idx < 676; idx += 640) {
        int r = idx / 26, cc = idx - r * 26;
        int gy = y0 + r - 5, gx = x0 + cc - 5;
        timg[r * 27 + cc] = (gy >= 0 && gy < 256 && gx >= 0 && gx < 256) ? im[gy * 256 + gx] : 0.f;
    }
    __syncthreads();

    int rr = lane >> 1;
    int half = lane & 1;
    if (rr < 26) {
        int cx0 = half * 8;
        float xv[18];
#pragma unroll
        for (int t = 0; t < 18; ++t) xv[t] = timg[rr * 27 + cx0 + t];
#pragma unroll
        for (int m = 0; m < 8; ++m) {
            float ar = 0.f, ai = 0.f;
#pragma unroll
            for (int j = 0; j < 11; ++j) {
                ar = fmaf(hr[j], xv[m + j], ar);
                ai = fmaf(hi[j], xv[m + j], ai);
            }
            inter[c][rr * 34 + 2 * (cx0 + m)]     = ar;
            inter[c][rr * 34 + 2 * (cx0 + m) + 1] = ai;
        }
    }
    __syncthreads();

    int x = lane & 15, yq = lane >> 4;
    int yb = 4 * yq;
    const float* sc = &inter[c][yb * 34 + 2 * x];
    float accr[4] = {0.f, 0.f, 0.f, 0.f};
    float acci[4] = {0.f, 0.f, 0.f, 0.f};
#pragma unroll
    for (int r = 0; r < 14; ++r) {
        float vr = sc[r * 34], vi = sc[r * 34 + 1];
#pragma unroll
        for (int dy = 0; dy < 4; ++dy) {
            if (r - dy >= 0 && r - dy <= 10) {
                float wr = fr[r - dy], wi = fi[r - dy];
                accr[dy] = fmaf(wr, vr, fmaf(-wi, vi, accr[dy]));
                acci[dy] = fmaf(wr, vi, fmaf(wi, vr, acci[dy]));
            }
        }
    }
    float* so = s1abs + (size_t)(n * 10 + c) * 65536 + (y0 + yb) * 256 + (x0 + x);
#pragma unroll
    for (int dy = 0; dy < 4; ++dy)
        so[dy * 256] = inv * sqrtf(accr[dy] * accr[dy] + acci[dy] * acci[dy]);
}

// ---------------- k_mainfix: composed 17x17 conv + border fix --------------
// bx 0..7: main y-band blocks (src = by).  bx 8..10: border-fix blocks.
__global__ __launch_bounds__(256, 3) void k_mainfix(const float* __restrict__ img,
                                                    const float* __restrict__ s1abs,
                                                    const float* __restrict__ combT,
                                                    const float* __restrict__ blur,
                                                    float* __restrict__ out) {
    __shared__ float tile[41 * 280];   // 45.9 KB
    int tid = threadIdx.x;
    int bx = blockIdx.x;

    if (bx < 8) {
        int src = blockIdx.y;
        int n = blockIdx.z;
        const float* sp = (src == 0) ? img + n * 65536
                                     : s1abs + (size_t)(n * 10 + src - 1) * 65536;
        int base_r = 32 * bx - 8;
        for (int idx = tid; idx < 41 * 273; idx += 256) {
            int r = idx / 273, cc = idx - r * 273;
            int gr = base_r + r, gc = cc - 8;
            float v = 0.f;
            if (gr >= 0 && gr < 256 && gc >= 0 && gc < 256) v = sp[gr * 256 + gc];
            tile[r * 280 + (cc & 7) * 35 + (cc >> 3)] = v;
        }
        __syncthreads();

        int X = tid & 31;
        int t2 = tid >> 5;
        int y = t2 & 3;
        int hu = (tid >> 7) & 1;   // NOT provably wave-uniform -> VMEM weight loads
        int Y = 4 * bx + y;

        float acc[5] = {0.f, 0.f, 0.f, 0.f, 0.f};
        const float* cw0 = combT + hu * 5;
        for (int i = 0; i < 17; ++i) {
            int vb = (8 * y + i) * 280 + X;
            const float* cwi = cw0 + i * 170;
#pragma unroll
            for (int j = 0; j < 17; ++j) {
                float xx = tile[vb + (j & 7) * 35 + (j >> 3)];
                const float* cw = cwi + j * 10;
#pragma unroll
                for (int kk = 0; kk < 5; ++kk)
                    acc[kk] = fmaf(xx, cw[kk], acc[kk]);
            }
        }

        size_t nb = (size_t)n * 111 * 1024;
        int ch0 = (src == 0) ? 1 : 11 + (src - 1) * 10;
        if (X > 0 && Y > 0) {          // borders handled by fix blocks
            float* ob = out + nb + (size_t)(ch0 + hu * 5) * 1024 + Y * 32 + X;
#pragma unroll
            for (int kk = 0; kk < 5; ++kk) ob[kk * 1024] = acc[kk];
        }

        if (src == 0 && hu == 0) {     // s0: exact clipped blur, all pixels
            float s0 = 0.f;
            for (int p = 0; p < 7; ++p) {
                int rb = (8 * y + p + 5) * 280 + X;
#pragma unroll
                for (int q = 0; q < 7; ++q) {
                    int cc = q + 5;
                    float xx = tile[rb + (cc & 7) * 35 + (cc >> 3)];
                    s0 = fmaf(blur[p * 7 + q], xx, s0);
                }
            }
            out[nb + Y * 32 + X] = s0;
        }
        return;
    }

    // ---- border-fix blocks: 264 blocks x 8 half-waves, 27 outputs each ----
    int id = (bx - 8) * 88 + blockIdx.y * 8 + blockIdx.z;   // 0..263
    int hw = tid >> 5;
    int lane = tid & 31;
    int u = id * 8 + hw;                                    // unit 0..2111
    for (int m = 0; m < 27; ++m) {
        int o = u + 2112 * m;
        if (o >= 55440) break;
        int b = o % 63;
        int t = o / 63;
        int c = t % 110 + 1;
        int n = t / 110;
        int Y, X;
        if (b < 32) { Y = 0; X = b; } else { Y = b - 31; X = 0; }
        int v = ((Y == 0) ? 2 : 0) | ((X == 0) ? 1 : 0);
        const float* in;
        int k;
        if (c < 11) { in = img + n * 65536; k = c - 1; }
        else {
            int c2 = c - 11;
            int g = c2 / 10;
            k = c2 - g * 10;
            in = s1abs + (size_t)(n * 10 + g) * 65536;
        }
        const float* cw = combT + v * 2890 + k;
        float acc = 0.f;
        for (int m2 = 0; m2 < 10; ++m2) {
            int t9 = lane + 32 * m2;
            if (t9 >= 289) break;
            int i = t9 / 17, j = t9 - i * 17;
            int r = 8 * Y + i - 8, cc = 8 * X + j - 8;
            float x = (r >= 0 && r < 256 && cc >= 0 && cc < 256) ? in[r * 256 + cc] : 0.f;
            acc = fmaf(x, cw[t9 * 10], acc);
        }
#pragma unroll
        for (int mask = 16; mask >= 1; mask >>= 1)
            acc += __shfl_xor(acc, mask);
        if (lane == 0)
            out[((size_t)n * 111 + c) * 1024 + Y * 32 + X] = acc;
    }
}

extern "C" void kernel_launch(void* const* d_in, const int* in_sizes, int n_in,
                              void* d_out, int out_size, void* d_ws, size_t ws_size,
                              hipStream_t stream) {
    const float* img    = (const float*)d_in[0];
    const float* psi_re = (const float*)d_in[1];
    const float* psi_im = (const float*)d_in[2];
    const float* blur   = (const float*)d_in[3];
    float* out = (float*)d_out;
    float* ws = (float*)d_ws;
    float* s1abs = ws + S1ABS_OFF;
    float* combT = ws + COMBT_OFF;

    dim3 g1(16, 16, 9);
    k_s1<<<g1, 640, 0, stream>>>(img, psi_re, psi_im, blur, s1abs, combT);

    dim3 g2(11, 11, 8);
    k_mainfix<<<g2, 256, 0, stream>>>(img, s1abs, combT, blur, out);
}

// Round 6
// 93.237 us; speedup vs baseline: 1.1873x; 1.1873x over previous
//
#include <hip/hip_runtime.h>
#include <math.h>

// ---------------------------------------------------------------------------
// ScatteringNetwork:
//   img [8,1,256,256] f32, psi_re/psi_im [10,1,11,11] f32, blur_k [7,7] f32
//   out: concat([s0(1ch), s1_out(10ch), s2_out(100ch)]) at 32x32 -> [8, 111*1024]
//
// blur(conv(x,psi))[::8] == conv(x, psi (*) blur)[::8]. blur = g (x) g (rank-1
// exact) and psi_k = F_k (x) H_k (rank-1 exact), so the composed 17x17 kernel
// is rank-2 separable: comb_k = Re(F'_k (x) H'_k) = F'r(x)H'r - F'i(x)H'i,
// F' = a (*) F (17 taps), H' = b (*) H, a_p = blur[p][3], b_q=blur[3][q]/blur[3][3].
// Blur-pad clipping at Y==0 / X==0 clips only a / b -> variant factors F'' / H''
// (still rank-1) -> NO separate border-fix pass needed.
//
// Weights per channel = 8*17 = 136 f32 -> register-resident per wave (the
// measured 6x lever: register-weight kernels ~12us, memory-weight ~85us).
//
// ws layout (floats): [0) s1abs 8*10*65536 ; [5242880) fhp 10*136
// fhp per ch: [0)H'r [17)H'i [34)H''r [51)H''i [68)F'r [85)F'i [102)F''r [119)F''i
// ---------------------------------------------------------------------------

#define S1ABS_OFF 0
#define FHP_OFF   5242880

// ---------------- k_s1: separable Morlet |conv|, wave-per-channel ----------
__global__ __launch_bounds__(640) void k_s1(const float* __restrict__ img,
                                            const float* __restrict__ psi_re,
                                            const float* __restrict__ psi_im,
                                            const float* __restrict__ blur,
                                            float* __restrict__ s1abs,
                                            float* __restrict__ fhp) {
    if (blockIdx.z == 8) {        // fhp setup slice
        int g = (blockIdx.y * 16 + blockIdx.x) * 640 + threadIdx.x;
        if (g < 1360) {
            int ch = g / 136;
            int w = g - ch * 136;
            int part = w / 17;
            int i = w - part * 17;
            const float* pr = psi_re + ch * 121;
            const float* pi = psi_im + ch * 121;
            float val = 0.f;
            if (part < 4) {                       // H-type: H_j = psi[5][j]
                int qmin = (part >= 2) ? 3 : 0;
                int comp = part & 1;
                float bden = blur[24];
                for (int q = qmin; q < 7; ++q) {
                    int jj = i - q;
                    if (jj < 0 || jj > 10) continue;
                    float bq = blur[21 + q] / bden;
                    float h = comp ? pi[55 + jj] : pr[55 + jj];
                    val += bq * h;
                }
            } else {                              // F-type: F_i = psi[i][5]/psi[5][5]
                int pmin = (part >= 6) ? 3 : 0;
                int comp = part & 1;
                float dr = pr[60], di = pi[60];
                float inv = 1.f / (dr * dr + di * di);
                for (int p = pmin; p < 7; ++p) {
                    int ii = i - p;
                    if (ii < 0 || ii > 10) continue;
                    float ap = blur[p * 7 + 3];
                    float nr = pr[ii * 11 + 5], ni = pi[ii * 11 + 5];
                    float f = comp ? (ni * dr - nr * di) * inv
                                   : (nr * dr + ni * di) * inv;
                    val += ap * f;
                }
            }
            fhp[g] = val;
        }
        return;
    }

    __shared__ float timg[26 * 27];
    __shared__ float inter[10][26 * 34];
    int tid = threadIdx.x;
    int lane = tid & 63;
    int c = __builtin_amdgcn_readfirstlane(tid >> 6);   // wave = channel 0..9

    const float* pr = psi_re + c * 121;
    const float* pi = psi_im + c * 121;
    float hr[11], hi[11], fr[11], fi[11];
#pragma unroll
    for (int j = 0; j < 11; ++j) { hr[j] = pr[55 + j]; hi[j] = pi[55 + j]; }
#pragma unroll
    for (int i = 0; i < 11; ++i) { fr[i] = pr[i * 11 + 5]; fi[i] = pi[i * 11 + 5]; }
    float dr = pr[60], di = pi[60];
    float inv = rsqrtf(dr * dr + di * di);

    int n = blockIdx.z;
    int y0 = blockIdx.y * 16, x0 = blockIdx.x * 16;
    const float* im = img + n * 65536;
    for (int idx = tid; idx < 676; idx += 640) {
        int r = idx / 26, cc = idx - r * 26;
        int gy = y0 + r - 5, gx = x0 + cc - 5;
        timg[r * 27 + cc] = (gy >= 0 && gy < 256 && gx >= 0 && gx < 256) ? im[gy * 256 + gx] : 0.f;
    }
    __syncthreads();

    int rr = lane >> 1;
    int half = lane & 1;
    if (rr < 26) {
        int cx0 = half * 8;
        float xv[18];
#pragma unroll
        for (int t = 0; t < 18; ++t) xv[t] = timg[rr * 27 + cx0 + t];
#pragma unroll
        for (int m = 0; m < 8; ++m) {
            float ar = 0.f, ai = 0.f;
#pragma unroll
            for (int j = 0; j < 11; ++j) {
                ar = fmaf(hr[j], xv[m + j], ar);
                ai = fmaf(hi[j], xv[m + j], ai);
            }
            inter[c][rr * 34 + 2 * (cx0 + m)]     = ar;
            inter[c][rr * 34 + 2 * (cx0 + m) + 1] = ai;
        }
    }
    __syncthreads();

    int x = lane & 15, yq = lane >> 4;
    int yb = 4 * yq;
    const float* sc = &inter[c][yb * 34 + 2 * x];
    float accr[4] = {0.f, 0.f, 0.f, 0.f};
    float acci[4] = {0.f, 0.f, 0.f, 0.f};
#pragma unroll
    for (int r = 0; r < 14; ++r) {
        float vr = sc[r * 34], vi = sc[r * 34 + 1];
#pragma unroll
        for (int dy = 0; dy < 4; ++dy) {
            if (r - dy >= 0 && r - dy <= 10) {
                float wr = fr[r - dy], wi = fi[r - dy];
                accr[dy] = fmaf(wr, vr, fmaf(-wi, vi, accr[dy]));
                acci[dy] = fmaf(wr, vi, fmaf(wi, vr, acci[dy]));
            }
        }
    }
    float* so = s1abs + (size_t)(n * 10 + c) * 65536 + (y0 + yb) * 256 + (x0 + x);
#pragma unroll
    for (int dy = 0; dy < 4; ++dy)
        so[dy * 256] = inv * sqrtf(accr[dy] * accr[dy] + acci[dy] * acci[dy]);
}

// ---------------- k_main2: rank-2 separable composed conv ------------------
// grid (16 Y-pair bands, 11 src, 8 n), 320 threads = 5 waves, 2 ch per wave.
__global__ __launch_bounds__(320) void k_main2(const float* __restrict__ img,
                                               const float* __restrict__ s1abs,
                                               const float* __restrict__ fhp,
                                               const float* __restrict__ blur,
                                               float* __restrict__ out) {
    __shared__ __align__(16) float tile[25 * 276];      // 27.6 KB
    __shared__ __align__(16) float inter[5][25 * 64];   // 32 KB
    int tid = threadIdx.x;
    int b = blockIdx.x;        // Y in {2b, 2b+1}
    int src = blockIdx.y;      // 0..10
    int n = blockIdx.z;

    const float* sp = (src == 0) ? img + n * 65536
                                 : s1abs + (size_t)(n * 10 + src - 1) * 65536;
    int gr0 = 16 * b - 8;
    for (int idx = tid; idx < 25 * 273; idx += 320) {
        int r = idx / 273, tc = idx - r * 273;
        int gr = gr0 + r, gc = tc - 8;
        float v = (gr >= 0 && gr < 256 && gc >= 0 && gc < 256) ? sp[gr * 256 + gc] : 0.f;
        tile[r * 276 + tc] = v;
    }
    __syncthreads();

    int wave = __builtin_amdgcn_readfirstlane(tid >> 6);
    int lane = tid & 63;
    float* isl = &inter[wave][0];
    size_t nb = (size_t)n * 111 * 1024;
    int ch0 = (src == 0) ? 1 : 11 + (src - 1) * 10;
    int Xc = lane & 31, ysub = lane >> 5;
    int Y = 2 * b + ysub;

    for (int q = 0; q < 2; ++q) {
        int ch = wave + 5 * q;
        const float* fc = fhp + ch * 136;
        float Hr[17], Hi[17];
#pragma unroll
        for (int j = 0; j < 17; ++j) { Hr[j] = fc[j]; Hi[j] = fc[17 + j]; }

        // row pass: R(rr, X) for rr 0..24, X 0..31 (tasks = rr*8 + xr, 4 X each)
        for (int t = lane; t < 200; t += 64) {
            int rr = t >> 3, xr = t & 7;
            const float* trow = &tile[rr * 276 + 32 * xr];
            float aR[4] = {0.f, 0.f, 0.f, 0.f};
            float aI[4] = {0.f, 0.f, 0.f, 0.f};
#pragma unroll
            for (int mc = 0; mc < 11; ++mc) {
                float4 xv = *(const float4*)(trow + 4 * mc);
#pragma unroll
                for (int e = 0; e < 4; ++e) {
                    int cidx = 4 * mc + e;
                    if (cidx > 40) break;            // static after unroll
                    float x = (&xv.x)[e];
#pragma unroll
                    for (int w = 0; w < 4; ++w) {
                        int j = cidx - 8 * w;
                        if (j >= 0 && j <= 16) {     // static after unroll
                            aR[w] = fmaf(Hr[j], x, aR[w]);
                            aI[w] = fmaf(Hi[j], x, aI[w]);
                        }
                    }
                }
            }
            float* dst = isl + rr * 64 + 8 * xr;
            float4 o0 = {aR[0], aI[0], aR[1], aI[1]};
            float4 o1 = {aR[2], aI[2], aR[3], aI[3]};
            *(float4*)dst = o0;
            *(float4*)(dst + 4) = o1;
        }

        // X==0 slot redo with clipped H'' (blur col-pad clip at X==0)
        if (lane < 25) {
            int rr = lane;
            float s_r = 0.f, s_i = 0.f;
#pragma unroll
            for (int j = 0; j < 17; ++j) {
                float x = tile[rr * 276 + j];
                s_r = fmaf(fc[34 + j], x, s_r);
                s_i = fmaf(fc[51 + j], x, s_i);
            }
            isl[rr * 64] = s_r;
            isl[rr * 64 + 1] = s_i;
        }

        // col pass: one output per lane; Y==0 uses clipped F''
        float acc = 0.f;
#pragma unroll
        for (int i = 0; i < 17; ++i) {
            float fr_ = (Y == 0) ? fc[102 + i] : fc[68 + i];
            float fi_ = (Y == 0) ? fc[119 + i] : fc[85 + i];
            float vr = isl[(8 * ysub + i) * 64 + 2 * Xc];
            float vi = isl[(8 * ysub + i) * 64 + 2 * Xc + 1];
            acc = fmaf(fr_, vr, acc);
            acc = fmaf(-fi_, vi, acc);
        }
        out[nb + (size_t)(ch0 + ch) * 1024 + Y * 32 + Xc] = acc;
    }

    // s0 = clipped 7x7 blur of img at stride 8 (zero-fill tile == zero-pad)
    if (src == 0 && wave == 0) {
        float s0 = 0.f;
#pragma unroll
        for (int p = 0; p < 7; ++p)
#pragma unroll
            for (int qq = 0; qq < 7; ++qq)
                s0 = fmaf(blur[p * 7 + qq], tile[(8 * ysub + p + 5) * 276 + 8 * Xc + qq + 5], s0);
        out[nb + Y * 32 + Xc] = s0;
    }
}

extern "C" void kernel_launch(void* const* d_in, const int* in_sizes, int n_in,
                              void* d_out, int out_size, void* d_ws, size_t ws_size,
                              hipStream_t stream) {
    const float* img    = (const float*)d_in[0];
    const float* psi_re = (const float*)d_in[1];
    const float* psi_im = (const float*)d_in[2];
    const float* blur   = (const float*)d_in[3];
    float* out = (float*)d_out;
    float* ws = (float*)d_ws;
    float* s1abs = ws + S1ABS_OFF;
    float* fhp   = ws + FHP_OFF;

    dim3 g1(16, 16, 9);
    k_s1<<<g1, 640, 0, stream>>>(img, psi_re, psi_im, blur, s1abs, fhp);

    dim3 g2(16, 11, 8);
    k_main2<<<g2, 320, 0, stream>>>(img, s1abs, fhp, blur, out);
}

// Round 7
// 72.856 us; speedup vs baseline: 1.5195x; 1.2798x over previous
//
#include <hip/hip_runtime.h>
#include <math.h>

// ---------------------------------------------------------------------------
// ScatteringNetwork:
//   img [8,1,256,256] f32, psi_re/psi_im [10,1,11,11] f32, blur_k [7,7] f32
//   out: concat([s0(1ch), s1_out(10ch), s2_out(100ch)]) at 32x32 -> [8, 111*1024]
//
// blur(conv(x,psi))[::8] == conv(x, psi (*) blur)[::8]. blur = g (x) g and
// psi_k = F_k (x) H_k (both rank-1 exact) -> composed 17x17 kernel is rank-2:
// comb_k = F'r(x)H'r - F'i(x)H'i, F' = a (*) F, H' = b (*) H. Blur-pad clip at
// Y==0 / X==0 only clips a / b -> variant factors F'' / H'' (rare paths).
//
// H'/F' are even(re)/odd(im) symmetric about tap 8 -> 9 regs per component.
// ALL hot-path weights register-resident (the measured 6x lever); H''/F''
// stay in rarely-executed exec-masked VMEM paths.
//
// ws layout (floats): [0) s1abs 8*10*65536 ; [5242880) fhp 10*136
// fhp per ch: [0)H'r [17)H'i [34)H''r [51)H''i [68)F'r [85)F'i [102)F''r [119)F''i
// ---------------------------------------------------------------------------

#define S1ABS_OFF 0
#define FHP_OFF   5242880

// ---------------- k_s1: separable Morlet |conv|, wave-per-channel ----------
__global__ __launch_bounds__(640) void k_s1(const float* __restrict__ img,
                                            const float* __restrict__ psi_re,
                                            const float* __restrict__ psi_im,
                                            const float* __restrict__ blur,
                                            float* __restrict__ s1abs,
                                            float* __restrict__ fhp) {
    if (blockIdx.z == 8) {        // fhp setup slice
        int g = (blockIdx.y * 16 + blockIdx.x) * 640 + threadIdx.x;
        if (g < 1360) {
            int ch = g / 136;
            int w = g - ch * 136;
            int part = w / 17;
            int i = w - part * 17;
            const float* pr = psi_re + ch * 121;
            const float* pi = psi_im + ch * 121;
            float val = 0.f;
            if (part < 4) {                       // H-type: H_j = psi[5][j]
                int qmin = (part >= 2) ? 3 : 0;
                int comp = part & 1;
                float bden = blur[24];
                for (int q = qmin; q < 7; ++q) {
                    int jj = i - q;
                    if (jj < 0 || jj > 10) continue;
                    float bq = blur[21 + q] / bden;
                    float h = comp ? pi[55 + jj] : pr[55 + jj];
                    val += bq * h;
                }
            } else {                              // F-type: F_i = psi[i][5]/psi[5][5]
                int pmin = (part >= 6) ? 3 : 0;
                int comp = part & 1;
                float dr = pr[60], di = pi[60];
                float inv = 1.f / (dr * dr + di * di);
                for (int p = pmin; p < 7; ++p) {
                    int ii = i - p;
                    if (ii < 0 || ii > 10) continue;
                    float ap = blur[p * 7 + 3];
                    float nr = pr[ii * 11 + 5], ni = pi[ii * 11 + 5];
                    float f = comp ? (ni * dr - nr * di) * inv
                                   : (nr * dr + ni * di) * inv;
                    val += ap * f;
                }
            }
            fhp[g] = val;
        }
        return;
    }

    __shared__ float timg[26 * 27];
    __shared__ float inter[10][26 * 34];
    int tid = threadIdx.x;
    int lane = tid & 63;
    int c = __builtin_amdgcn_readfirstlane(tid >> 6);   // wave = channel 0..9

    const float* pr = psi_re + c * 121;
    const float* pi = psi_im + c * 121;
    float hr[11], hi[11], fr[11], fi[11];
#pragma unroll
    for (int j = 0; j < 11; ++j) { hr[j] = pr[55 + j]; hi[j] = pi[55 + j]; }
#pragma unroll
    for (int i = 0; i < 11; ++i) { fr[i] = pr[i * 11 + 5]; fi[i] = pi[i * 11 + 5]; }
    float dr = pr[60], di = pi[60];
    float inv = rsqrtf(dr * dr + di * di);

    int n = blockIdx.z;
    int y0 = blockIdx.y * 16, x0 = blockIdx.x * 16;
    const float* im = img + n * 65536;
    for (int idx = tid; idx < 676; idx += 640) {
        int r = idx / 26, cc = idx - r * 26;
        int gy = y0 + r - 5, gx = x0 + cc - 5;
        timg[r * 27 + cc] = (gy >= 0 && gy < 256 && gx >= 0 && gx < 256) ? im[gy * 256 + gx] : 0.f;
    }
    __syncthreads();

    int rr = lane >> 1;
    int half = lane & 1;
    if (rr < 26) {
        int cx0 = half * 8;
        float xv[18];
#pragma unroll
        for (int t = 0; t < 18; ++t) xv[t] = timg[rr * 27 + cx0 + t];
#pragma unroll
        for (int m = 0; m < 8; ++m) {
            float ar = 0.f, ai = 0.f;
#pragma unroll
            for (int j = 0; j < 11; ++j) {
                ar = fmaf(hr[j], xv[m + j], ar);
                ai = fmaf(hi[j], xv[m + j], ai);
            }
            inter[c][rr * 34 + 2 * (cx0 + m)]     = ar;
            inter[c][rr * 34 + 2 * (cx0 + m) + 1] = ai;
        }
    }
    __syncthreads();

    int x = lane & 15, yq = lane >> 4;
    int yb = 4 * yq;
    const float* sc = &inter[c][yb * 34 + 2 * x];
    float accr[4] = {0.f, 0.f, 0.f, 0.f};
    float acci[4] = {0.f, 0.f, 0.f, 0.f};
#pragma unroll
    for (int r = 0; r < 14; ++r) {
        float vr = sc[r * 34], vi = sc[r * 34 + 1];
#pragma unroll
        for (int dy = 0; dy < 4; ++dy) {
            if (r - dy >= 0 && r - dy <= 10) {
                float wr = fr[r - dy], wi = fi[r - dy];
                accr[dy] = fmaf(wr, vr, fmaf(-wi, vi, accr[dy]));
                acci[dy] = fmaf(wr, vi, fmaf(wi, vr, acci[dy]));
            }
        }
    }
    float* so = s1abs + (size_t)(n * 10 + c) * 65536 + (y0 + yb) * 256 + (x0 + x);
#pragma unroll
    for (int dy = 0; dy < 4; ++dy)
        so[dy * 256] = inv * sqrtf(accr[dy] * accr[dy] + acci[dy] * acci[dy]);
}

// ---------------- k_main3: rank-2 separable composed conv ------------------
// grid (32 = 16 Ybands x 2 Xhalves, 11 src, 8 n), 320 thr = 5 waves x 2 ch.
__global__ __launch_bounds__(320) void k_main3(const float* __restrict__ img,
                                               const float* __restrict__ s1abs,
                                               const float* __restrict__ fhp,
                                               const float* __restrict__ blur,
                                               float* __restrict__ out) {
    __shared__ __align__(16) float tile[25 * 148];       // 14.8 KB
    __shared__ __align__(16) float inter[10][25 * 36];   // 36 KB
    int tid = threadIdx.x;
    int bx = blockIdx.x;
    int b = bx >> 1, h = bx & 1;   // Y in {2b,2b+1}, X in [16h,16h+16)
    int src = blockIdx.y;          // 0..10
    int n = blockIdx.z;

    const float* sp = (src == 0) ? img + n * 65536
                                 : s1abs + (size_t)(n * 10 + src - 1) * 65536;
    int gr0 = 16 * b - 8;
    int gc0 = 128 * h - 8;
    for (int idx = tid; idx < 25 * 145; idx += 320) {
        int r = idx / 145, cc = idx - r * 145;
        int gr = gr0 + r, gc = gc0 + cc;
        float v = (gr >= 0 && gr < 256 && gc >= 0 && gc < 256) ? sp[gr * 256 + gc] : 0.f;
        tile[r * 148 + cc] = v;
    }

    int wave = __builtin_amdgcn_readfirstlane(tid >> 6);
    int lane = tid & 63;
    int chA = wave, chB = wave + 5;
    const float* fA = fhp + chA * 136;
    const float* fB = fhp + chB * 136;
    // H' register preload, symmetric storage (Hr even, Hi odd about tap 8)
    float HrA[9], HiA[9], HrB[9], HiB[9];
#pragma unroll
    for (int j = 0; j < 9; ++j) {
        HrA[j] = fA[j]; HiA[j] = fA[17 + j];
        HrB[j] = fB[j]; HiB[j] = fB[17 + j];
    }
    __syncthreads();

    float* iA = &inter[wave * 2][0];
    float* iB = &inter[wave * 2 + 1][0];

    // row pass: tasks (rr 0..24, xr 0..3), 4 X-outputs per task, both channels
#pragma unroll
    for (int it = 0; it < 2; ++it) {
        int t = lane + 64 * it;
        if (t < 100) {
            int rr = t % 25, xr = t / 25;
            const float* trow = &tile[rr * 148 + 32 * xr];
            float aR[4] = {0.f,0.f,0.f,0.f}, aI[4] = {0.f,0.f,0.f,0.f};
            float bR[4] = {0.f,0.f,0.f,0.f}, bI[4] = {0.f,0.f,0.f,0.f};
#pragma unroll
            for (int mc = 0; mc < 11; ++mc) {
                float4 xv = *(const float4*)(trow + 4 * mc);
#pragma unroll
                for (int e = 0; e < 4; ++e) {
                    int cidx = 4 * mc + e;
                    float x = (&xv.x)[e];
#pragma unroll
                    for (int w = 0; w < 4; ++w) {
                        int j = cidx - 8 * w;
                        if (j >= 0 && j <= 16) {           // static after unroll
                            int jm = (j < 9) ? j : 16 - j;
                            aR[w] = fmaf(HrA[jm], x, aR[w]);
                            aI[w] = fmaf((j < 9) ? HiA[jm] : -HiA[jm], x, aI[w]);
                            bR[w] = fmaf(HrB[jm], x, bR[w]);
                            bI[w] = fmaf((j < 9) ? HiB[jm] : -HiB[jm], x, bI[w]);
                        }
                    }
                }
            }
            float* dA = iA + rr * 36 + 8 * xr;
            float* dB = iB + rr * 36 + 8 * xr;
            float4 a0 = {aR[0], aI[0], aR[1], aI[1]};
            float4 a1 = {aR[2], aI[2], aR[3], aI[3]};
            float4 b0 = {bR[0], bI[0], bR[1], bI[1]};
            float4 b1 = {bR[2], bI[2], bR[3], bI[3]};
            *(float4*)dA = a0; *(float4*)(dA + 4) = a1;
            *(float4*)dB = b0; *(float4*)(dB + 4) = b1;
        }
    }

    // X global == 0 slot redo with clipped H'' (h==0 blocks only)
    if (h == 0 && lane < 25) {
        int rr = lane;
        float sRA = 0.f, sIA = 0.f, sRB = 0.f, sIB = 0.f;
#pragma unroll
        for (int j = 0; j < 17; ++j) {
            float x = tile[rr * 148 + j];
            sRA = fmaf(fA[34 + j], x, sRA);
            sIA = fmaf(fA[51 + j], x, sIA);
            sRB = fmaf(fB[34 + j], x, sRB);
            sIB = fmaf(fB[51 + j], x, sIB);
        }
        iA[rr * 36] = sRA; iA[rr * 36 + 1] = sIA;
        iB[rr * 36] = sRB; iB[rr * 36 + 1] = sIB;
    }

    // col pass: lane = (q:2, ysub:2, Xc:16) -> one output each
    int q = lane >> 5;
    int ysub = (lane >> 4) & 1;
    int Xc = lane & 15;
    int Y = 2 * b + ysub;
    const float* fq = q ? fB : fA;
    const float* isl = q ? iB : iA;
    float Fr[9], Fi[9];
#pragma unroll
    for (int i = 0; i < 9; ++i) { Fr[i] = fq[68 + i]; Fi[i] = fq[85 + i]; }
    float acc = 0.f;
#pragma unroll
    for (int i = 0; i < 17; ++i) {
        float vr = isl[(8 * ysub + i) * 36 + 2 * Xc];
        float vi = isl[(8 * ysub + i) * 36 + 2 * Xc + 1];
        int im_ = (i < 9) ? i : 16 - i;
        float fr_ = Fr[im_];
        float fi_ = (i < 9) ? Fi[im_] : -Fi[im_];
        acc = fmaf(fr_, vr, acc);
        acc = fmaf(-fi_, vi, acc);
    }
    if (Y == 0) {                 // b==0 blocks: recompute with clipped F''
        acc = 0.f;
#pragma unroll
        for (int i = 0; i < 17; ++i) {
            float vr = isl[i * 36 + 2 * Xc];
            float vi = isl[i * 36 + 2 * Xc + 1];
            acc = fmaf(fq[102 + i], vr, acc);
            acc = fmaf(-fq[119 + i], vi, acc);
        }
    }
    int ch = q ? chB : chA;
    int ch_out = (src == 0) ? 1 + ch : 11 + (src - 1) * 10 + ch;
    size_t nb = (size_t)n * 111 * 1024;
    out[nb + (size_t)ch_out * 1024 + Y * 32 + 16 * h + Xc] = acc;

    // s0: exact clipped 7x7 blur at stride 8 (zero-fill tile == zero-pad)
    if (src == 0 && wave == 0 && lane < 32) {
        int ys = lane >> 4, Xs = lane & 15;
        float s0 = 0.f;
#pragma unroll
        for (int p = 0; p < 7; ++p)
#pragma unroll
            for (int qq = 0; qq < 7; ++qq)
                s0 = fmaf(blur[p * 7 + qq], tile[(8 * ys + p + 5) * 148 + 8 * Xs + qq + 5], s0);
        out[nb + (2 * b + ys) * 32 + 16 * h + Xs] = s0;
    }
}

extern "C" void kernel_launch(void* const* d_in, const int* in_sizes, int n_in,
                              void* d_out, int out_size, void* d_ws, size_t ws_size,
                              hipStream_t stream) {
    const float* img    = (const float*)d_in[0];
    const float* psi_re = (const float*)d_in[1];
    const float* psi_im = (const float*)d_in[2];
    const float* blur   = (const float*)d_in[3];
    float* out = (float*)d_out;
    float* ws = (float*)d_ws;
    float* s1abs = ws + S1ABS_OFF;
    float* fhp   = ws + FHP_OFF;

    dim3 g1(16, 16, 9);
    k_s1<<<g1, 640, 0, stream>>>(img, psi_re, psi_im, blur, s1abs, fhp);

    dim3 g2(32, 11, 8);
    k_main3<<<g2, 320, 0, stream>>>(img, s1abs, fhp, blur, out);
}